// Round 4
// baseline (1637.841 us; speedup 1.0000x reference)
//
#include <hip/hip_runtime.h>

#define N 8192
#define TPB 1024
#define NW (TPB / 64)             // 16 waves per block
#define ROWS_PER_BLK 32
#define NBLK (N / ROWS_PER_BLK)   // 256 blocks == 1 per CU
#define RB 4                      // rows per batch (one barrier per batch)
#define NBATCH (ROWS_PER_BLK / RB)

// ---------------------------------------------------------------------------
// Fused pass over a 32-row chunk, max-free math:
//   e_ij = exp(A_ij - c_j); R_i = sum_j e_ij; r_i = log R_i
//   partial col sum  pl[blk][j] = sum_i e_ij / R_i      (then c += log sum_k pl)
// Thread t owns columns {4t..4t+3} and {4096+4t..+3} (coalesced float4).
// Software-pipelined: batch i+1 loads issue before batch i compute.
// ---------------------------------------------------------------------------
__global__ __launch_bounds__(TPB, 4) void fused_pass_kernel(
    const float* __restrict__ A,
    const float* __restrict__ c,
    float* __restrict__ r,
    float* __restrict__ pl,      // [NBLK][N] plain partial sums
    int use_c)
{
    const int t    = threadIdx.x;
    const int lane = t & 63;
    const int wave = t >> 6;
    const int blk  = blockIdx.x;
    const int row0 = blk * ROWS_PER_BLK;

    const float4* __restrict__ c4 = (const float4*)c;
    float4 cc0, cc1;
    if (use_c) { cc0 = c4[t]; cc1 = c4[t + TPB]; }
    else {
        cc0 = make_float4(0.f, 0.f, 0.f, 0.f);
        cc1 = cc0;
    }

    float4 acc0 = make_float4(0.f, 0.f, 0.f, 0.f);
    float4 acc1 = acc0;

    __shared__ float ls[2][RB][NW];   // double-buffered wave row-sums

    float4 va[RB][2], vb[RB][2];

#define LOADB(BUF, B)                                                         \
    {                                                                         \
        _Pragma("unroll")                                                     \
        for (int rr = 0; rr < RB; ++rr) {                                     \
            const float4* __restrict__ Ar =                                   \
                (const float4*)(A + (size_t)(row0 + (B) * RB + rr) * N);      \
            BUF[rr][0] = Ar[t];                                               \
            BUF[rr][1] = Ar[t + TPB];                                         \
        }                                                                     \
    }

#define PROCB(BUF, B, LSB)                                                    \
    {                                                                         \
        float ts[RB];                                                         \
        _Pragma("unroll")                                                     \
        for (int rr = 0; rr < RB; ++rr) {                                     \
            float4 e0, e1;                                                    \
            e0.x = __expf(BUF[rr][0].x - cc0.x);                              \
            e0.y = __expf(BUF[rr][0].y - cc0.y);                              \
            e0.z = __expf(BUF[rr][0].z - cc0.z);                              \
            e0.w = __expf(BUF[rr][0].w - cc0.w);                              \
            e1.x = __expf(BUF[rr][1].x - cc1.x);                              \
            e1.y = __expf(BUF[rr][1].y - cc1.y);                              \
            e1.z = __expf(BUF[rr][1].z - cc1.z);                              \
            e1.w = __expf(BUF[rr][1].w - cc1.w);                              \
            BUF[rr][0] = e0;                                                  \
            BUF[rr][1] = e1;                                                  \
            ts[rr] = ((e0.x + e0.y) + (e0.z + e0.w)) +                        \
                     ((e1.x + e1.y) + (e1.z + e1.w));                         \
        }                                                                     \
        _Pragma("unroll")                                                     \
        for (int rr = 0; rr < RB; ++rr) {                                     \
            _Pragma("unroll")                                                 \
            for (int off = 32; off > 0; off >>= 1)                            \
                ts[rr] += __shfl_xor(ts[rr], off);                            \
        }                                                                     \
        if (lane == 0) {                                                      \
            ls[LSB][0][wave] = ts[0];                                         \
            ls[LSB][1][wave] = ts[1];                                         \
            ls[LSB][2][wave] = ts[2];                                         \
            ls[LSB][3][wave] = ts[3];                                         \
        }                                                                     \
        __syncthreads();                                                      \
        float R0 = ls[LSB][0][lane & 15];                                     \
        float R1 = ls[LSB][1][lane & 15];                                     \
        float R2 = ls[LSB][2][lane & 15];                                     \
        float R3 = ls[LSB][3][lane & 15];                                     \
        _Pragma("unroll")                                                     \
        for (int off = 1; off < 16; off <<= 1) {                              \
            R0 += __shfl_xor(R0, off);                                        \
            R1 += __shfl_xor(R1, off);                                        \
            R2 += __shfl_xor(R2, off);                                        \
            R3 += __shfl_xor(R3, off);                                        \
        }                                                                     \
        if (t == 0) {                                                         \
            float4 rv;                                                        \
            rv.x = __logf(R0); rv.y = __logf(R1);                             \
            rv.z = __logf(R2); rv.w = __logf(R3);                             \
            *(float4*)(r + row0 + (B) * RB) = rv;                             \
        }                                                                     \
        const float i0 = 1.0f / R0, i1 = 1.0f / R1;                           \
        const float i2 = 1.0f / R2, i3 = 1.0f / R3;                           \
        acc0.x = __fmaf_rn(BUF[0][0].x, i0, acc0.x);                          \
        acc0.y = __fmaf_rn(BUF[0][0].y, i0, acc0.y);                          \
        acc0.z = __fmaf_rn(BUF[0][0].z, i0, acc0.z);                          \
        acc0.w = __fmaf_rn(BUF[0][0].w, i0, acc0.w);                          \
        acc1.x = __fmaf_rn(BUF[0][1].x, i0, acc1.x);                          \
        acc1.y = __fmaf_rn(BUF[0][1].y, i0, acc1.y);                          \
        acc1.z = __fmaf_rn(BUF[0][1].z, i0, acc1.z);                          \
        acc1.w = __fmaf_rn(BUF[0][1].w, i0, acc1.w);                          \
        acc0.x = __fmaf_rn(BUF[1][0].x, i1, acc0.x);                          \
        acc0.y = __fmaf_rn(BUF[1][0].y, i1, acc0.y);                          \
        acc0.z = __fmaf_rn(BUF[1][0].z, i1, acc0.z);                          \
        acc0.w = __fmaf_rn(BUF[1][0].w, i1, acc0.w);                          \
        acc1.x = __fmaf_rn(BUF[1][1].x, i1, acc1.x);                          \
        acc1.y = __fmaf_rn(BUF[1][1].y, i1, acc1.y);                          \
        acc1.z = __fmaf_rn(BUF[1][1].z, i1, acc1.z);                          \
        acc1.w = __fmaf_rn(BUF[1][1].w, i1, acc1.w);                          \
        acc0.x = __fmaf_rn(BUF[2][0].x, i2, acc0.x);                          \
        acc0.y = __fmaf_rn(BUF[2][0].y, i2, acc0.y);                          \
        acc0.z = __fmaf_rn(BUF[2][0].z, i2, acc0.z);                          \
        acc0.w = __fmaf_rn(BUF[2][0].w, i2, acc0.w);                          \
        acc1.x = __fmaf_rn(BUF[2][1].x, i2, acc1.x);                          \
        acc1.y = __fmaf_rn(BUF[2][1].y, i2, acc1.y);                          \
        acc1.z = __fmaf_rn(BUF[2][1].z, i2, acc1.z);                          \
        acc1.w = __fmaf_rn(BUF[2][1].w, i2, acc1.w);                          \
        acc0.x = __fmaf_rn(BUF[3][0].x, i3, acc0.x);                          \
        acc0.y = __fmaf_rn(BUF[3][0].y, i3, acc0.y);                          \
        acc0.z = __fmaf_rn(BUF[3][0].z, i3, acc0.z);                          \
        acc0.w = __fmaf_rn(BUF[3][0].w, i3, acc0.w);                          \
        acc1.x = __fmaf_rn(BUF[3][1].x, i3, acc1.x);                          \
        acc1.y = __fmaf_rn(BUF[3][1].y, i3, acc1.y);                          \
        acc1.z = __fmaf_rn(BUF[3][1].z, i3, acc1.z);                          \
        acc1.w = __fmaf_rn(BUF[3][1].w, i3, acc1.w);                          \
    }

    // Fully unrolled software pipeline: load batch i+1 before processing i.
    LOADB(va, 0)
    LOADB(vb, 1) PROCB(va, 0, 0)
    LOADB(va, 2) PROCB(vb, 1, 1)
    LOADB(vb, 3) PROCB(va, 2, 0)
    LOADB(va, 4) PROCB(vb, 3, 1)
    LOADB(vb, 5) PROCB(va, 4, 0)
    LOADB(va, 6) PROCB(vb, 5, 1)
    LOADB(vb, 7) PROCB(va, 6, 0)
    PROCB(vb, 7, 1)

#undef LOADB
#undef PROCB

    float4* __restrict__ pl4 = (float4*)(pl + (size_t)blk * N);
    pl4[t]       = acc0;
    pl4[t + TPB] = acc1;
}

// ---------------------------------------------------------------------------
// Combine NBLK partial column sums: c[j] = (add_c ? c[j] : 0) + log(sum_k pl).
// ---------------------------------------------------------------------------
__global__ __launch_bounds__(256) void col_reduce_kernel(const float* __restrict__ pl,
                                                         float* __restrict__ c,
                                                         int add_c)
{
    const int col = blockIdx.x * 256 + threadIdx.x;
    float S = 0.f;
#pragma unroll 8
    for (int k = 0; k < NBLK; ++k)
        S += pl[(size_t)k * N + col];
    const float v = __logf(S);
    c[col] = add_c ? (c[col] + v) : v;
}

// ---------------------------------------------------------------------------
// Final: out[i][j] = exp(A[i][j] - r[i] - c[j])
// ---------------------------------------------------------------------------
__global__ __launch_bounds__(256) void finalize_kernel(const float* __restrict__ A,
                                                       const float* __restrict__ r,
                                                       const float* __restrict__ c,
                                                       float* __restrict__ out)
{
    const int row = blockIdx.x;
    const int t   = threadIdx.x;
    const float rr = r[row];
    const float4* __restrict__ Ar = (const float4*)(A + (size_t)row * N);
    const float4* __restrict__ c4 = (const float4*)c;
    float4* __restrict__ Or = (float4*)(out + (size_t)row * N);
#pragma unroll
    for (int k = 0; k < 8; ++k) {
        const int idx = t + (k << 8);
        float4 a  = Ar[idx];
        float4 cc = c4[idx];
        float4 o;
        o.x = __expf(a.x - rr - cc.x);
        o.y = __expf(a.y - rr - cc.y);
        o.z = __expf(a.z - rr - cc.z);
        o.w = __expf(a.w - rr - cc.w);
        Or[idx] = o;
    }
}

extern "C" void kernel_launch(void* const* d_in, const int* in_sizes, int n_in,
                              void* d_out, int out_size, void* d_ws, size_t ws_size,
                              hipStream_t stream)
{
    const float* A = (const float*)d_in[0];
    float* out = (float*)d_out;

    // r, c in workspace (64 KB).
    float* r = (float*)d_ws;             // N floats
    float* c = r + N;                    // N floats

    // Partial column sums live in d_out scratch (NBLK*N*4 = 8 MB out of
    // 256 MB); finalize_kernel fully overwrites d_out afterwards.
    float* pl = out;

    for (int it = 0; it < 10; ++it) {
        hipLaunchKernelGGL(fused_pass_kernel, dim3(NBLK), dim3(TPB), 0, stream,
                           A, c, r, pl, it /* use_c: 0 on first iteration */);
        hipLaunchKernelGGL(col_reduce_kernel, dim3(N / 256), dim3(256), 0, stream,
                           pl, c, it /* add_c: 0 on first iteration */);
    }
    hipLaunchKernelGGL(finalize_kernel, dim3(N), dim3(256), 0, stream, A, r, c, out);
}